// Round 2
// baseline (303.061 us; speedup 1.0000x reference)
//
#include <hip/hip_runtime.h>
#include <hip/hip_bf16.h>
#include <math.h>

#define BB 8
#define NN 2048
#define DD 128
#define ALPHA 0.2f

#define TI 32   // i-rows per block
#define TJ 64   // j columns per tile

// ---------------- Kernel A: f1 = h@a1, f2 = h@a2 (wave per row) ----------------
__global__ __launch_bounds__(256) void fscore_kernel(const float* __restrict__ h,
                                                     const float* __restrict__ a1,
                                                     const float* __restrict__ a2,
                                                     float* __restrict__ f1,
                                                     float* __restrict__ f2) {
    int row  = blockIdx.x * 4 + (threadIdx.x >> 6);   // [0, BB*NN)
    int lane = threadIdx.x & 63;
    const float2 hv  = *reinterpret_cast<const float2*>(h  + (size_t)row * DD + lane * 2);
    const float2 av1 = *reinterpret_cast<const float2*>(a1 + lane * 2);
    const float2 av2 = *reinterpret_cast<const float2*>(a2 + lane * 2);
    float s1 = hv.x * av1.x + hv.y * av1.y;
    float s2 = hv.x * av2.x + hv.y * av2.y;
#pragma unroll
    for (int off = 32; off > 0; off >>= 1) {
        s1 += __shfl_xor(s1, off, 64);
        s2 += __shfl_xor(s2, off, 64);
    }
    if (lane == 0) { f1[row] = s1; f2[row] = s2; }
}

// ---------------- Kernel B: masked softmax + aggregation + ELU ----------------
__global__ __launch_bounds__(256) void gat_main(const float* __restrict__ h,
                                                const int*   __restrict__ adj,
                                                const float* __restrict__ f1,
                                                const float* __restrict__ f2,
                                                float* __restrict__ out) {
    __shared__ __align__(16) float htile[TJ][DD];      // 32 KB
    __shared__ __align__(16) float wtile[TJ][TI + 4];  // 9216 B (pad 4 -> 16B-aligned rows, bank spread)
    __shared__ float sfin[TI];

    // XCD swizzle: dispatch n -> XCD n%8 (round-robin). Give XCD k batch k's 64 blocks.
    int n = blockIdx.x;
    int logical = (n & 7) * 64 + (n >> 3);   // bijective, 512 % 8 == 0
    int b  = logical >> 6;
    int i0 = (logical & 63) * TI;

    int t  = threadIdx.x;
    // w-phase mapping: thread owns column jj, i-range ib*8..ib*8+7
    int jj = t & 63;
    int ib = t >> 6;
    // compute mapping: i-group ig (4 rows), d-group dg (4 cols)
    int ig = t & 7;
    int dg = t >> 3;

    const float* hb     = h   + (size_t)b * NN * DD;
    const int*   adjrow = adj + (size_t)b * NN * NN + (size_t)(i0 + ib * 8) * NN;
    const float* f2b    = f2  + b * NN;

    float f1r[8];
#pragma unroll
    for (int k = 0; k < 8; ++k) f1r[k] = f1[b * NN + i0 + ib * 8 + k];

    float acc[4][4];
#pragma unroll
    for (int a = 0; a < 4; ++a)
#pragma unroll
        for (int c = 0; c < 4; ++c) acc[a][c] = 0.f;
    float sacc[8];
#pragma unroll
    for (int k = 0; k < 8; ++k) sacc[k] = 0.f;

    for (int j0 = 0; j0 < NN; j0 += TJ) {
        // ---- stage h[j0..j0+TJ) tile: 8 x float4 per thread, coalesced ----
#pragma unroll
        for (int m = 0; m < (TJ * DD) / (256 * 4); ++m) {
            int off = t * 4 + m * 1024;
            *reinterpret_cast<float4*>(&htile[0][0] + off) =
                *reinterpret_cast<const float4*>(hb + (size_t)j0 * DD + off);
        }
        // ---- w phase: w = adj ? exp(lrelu(f1_i + f2_j)) : 0 ----
        float f2v = f2b[j0 + jj];
        float wv[8];
#pragma unroll
        for (int k = 0; k < 8; ++k) {
            int a = adjrow[(size_t)k * NN + j0 + jj];
            float x = f1r[k] + f2v;
            float e = fmaxf(x, ALPHA * x);           // LeakyReLU (monotone)
            float w = (a > 0) ? __expf(e) : 0.f;     // no max-subtraction: bounded range
            wv[k] = w;
            sacc[k] += w;
        }
#pragma unroll
        for (int k = 0; k < 8; k += 4) {
            float4 v = make_float4(wv[k], wv[k + 1], wv[k + 2], wv[k + 3]);
            *reinterpret_cast<float4*>(&wtile[jj][ib * 8 + k]) = v;
        }
        __syncthreads();
        // ---- compute: 4i x 4d register outer product over TJ ----
#pragma unroll 4
        for (int j = 0; j < TJ; ++j) {
            float4 w4 = *reinterpret_cast<const float4*>(&wtile[j][ig * 4]);
            float4 h4 = *reinterpret_cast<const float4*>(&htile[j][dg * 4]);
            acc[0][0] += w4.x * h4.x; acc[0][1] += w4.x * h4.y; acc[0][2] += w4.x * h4.z; acc[0][3] += w4.x * h4.w;
            acc[1][0] += w4.y * h4.x; acc[1][1] += w4.y * h4.y; acc[1][2] += w4.y * h4.z; acc[1][3] += w4.y * h4.w;
            acc[2][0] += w4.z * h4.x; acc[2][1] += w4.z * h4.y; acc[2][2] += w4.z * h4.z; acc[2][3] += w4.z * h4.w;
            acc[3][0] += w4.w * h4.x; acc[3][1] += w4.w * h4.y; acc[3][2] += w4.w * h4.z; acc[3][3] += w4.w * h4.w;
        }
        __syncthreads();
    }

    // ---- denominator reduction: sacc -> wtile -> sfin ----
#pragma unroll
    for (int k = 0; k < 8; k += 4) {
        float4 v = make_float4(sacc[k], sacc[k + 1], sacc[k + 2], sacc[k + 3]);
        *reinterpret_cast<float4*>(&wtile[jj][ib * 8 + k]) = v;
    }
    __syncthreads();
    if (t < TI) {
        float s = 0.f;
#pragma unroll 8
        for (int q = 0; q < 64; ++q) s += wtile[q][t];
        sfin[t] = s;
    }
    __syncthreads();

    // ---- epilogue: elu(acc / s) -> LDS bounce -> coalesced store ----
    float* otile = &htile[0][0];   // reuse as [TI][DD]
#pragma unroll
    for (int k = 0; k < 4; ++k) {
        int i = ig * 4 + k;
        float sv = sfin[i];
        float r0 = acc[k][0] / sv, r1 = acc[k][1] / sv, r2 = acc[k][2] / sv, r3 = acc[k][3] / sv;
        r0 = (r0 > 0.f) ? r0 : expm1f(r0);
        r1 = (r1 > 0.f) ? r1 : expm1f(r1);
        r2 = (r2 > 0.f) ? r2 : expm1f(r2);
        r3 = (r3 > 0.f) ? r3 : expm1f(r3);
        *reinterpret_cast<float4*>(otile + i * DD + dg * 4) = make_float4(r0, r1, r2, r3);
    }
    __syncthreads();
    float* ob = out + (size_t)b * NN * DD + (size_t)i0 * DD;
#pragma unroll
    for (int m = 0; m < (TI * DD) / (256 * 4); ++m) {
        int off = t * 4 + m * 1024;
        *reinterpret_cast<float4*>(ob + off) = *reinterpret_cast<const float4*>(otile + off);
    }
}

extern "C" void kernel_launch(void* const* d_in, const int* in_sizes, int n_in,
                              void* d_out, int out_size, void* d_ws, size_t ws_size,
                              hipStream_t stream) {
    const float* h   = (const float*)d_in[0];
    const int*   adj = (const int*)d_in[1];
    const float* a1  = (const float*)d_in[2];
    const float* a2  = (const float*)d_in[3];
    float* out = (float*)d_out;

    float* f1 = (float*)d_ws;                 // BB*NN floats
    float* f2 = f1 + BB * NN;                 // BB*NN floats

    fscore_kernel<<<(BB * NN) / 4, 256, 0, stream>>>(h, a1, a2, f1, f2);
    gat_main<<<BB * (NN / TI), 256, 0, stream>>>(h, adj, f1, f2, out);
}

// Round 3
// 219.446 us; speedup vs baseline: 1.3810x; 1.3810x over previous
//
#include <hip/hip_runtime.h>
#include <hip/hip_bf16.h>
#include <math.h>

#define BB 8
#define NN 2048
#define DD 128
#define ALPHA 0.2f

typedef __attribute__((ext_vector_type(8))) short short8;
typedef __attribute__((ext_vector_type(4))) float f32x4;

__device__ inline unsigned short bf16_rne(float v) {
    unsigned int x = __float_as_uint(v);
    unsigned int r = x + 0x7FFFu + ((x >> 16) & 1u);   // round-to-nearest-even
    return (unsigned short)(r >> 16);
}
__device__ inline float bf16_back(unsigned short u) {
    return __uint_as_float(((unsigned int)u) << 16);
}

// ---------------- Kernel 1: f1/f2 scores + bf16 H^T panel pack ----------------
// Panel layout (per batch): [ks=0..63][n=0..127][c=0..3][e=0..7] bf16,
// element = h[ks*32 + c*8 + e][n]. One wave B-frag load = 1KB contiguous.
__global__ __launch_bounds__(256) void pack_kernel(const float* __restrict__ h,
                                                   const float* __restrict__ a1,
                                                   const float* __restrict__ a2,
                                                   float* __restrict__ f1,
                                                   float* __restrict__ f2,
                                                   unsigned short* __restrict__ panel) {
    __shared__ float hs[32][DD];   // 16 KB
    int blk = blockIdx.x;
    int b   = blk >> 6;            // 64 chunks of 32 rows per batch
    int ks  = blk & 63;
    int r0  = ks * 32;
    int t   = threadIdx.x;

    const float* hb = h + ((size_t)b * NN + r0) * DD;
#pragma unroll
    for (int m = 0; m < 4; ++m) {
        int off = t * 4 + m * 1024;
        *reinterpret_cast<float4*>(&hs[0][0] + off) =
            *reinterpret_cast<const float4*>(hb + off);
    }
    __syncthreads();

    // f-scores: 8 threads per row, 16 d each, shfl-reduce within 8-lane group
    {
        int row = t >> 3, d0 = (t & 7) * 16;
        float s1 = 0.f, s2 = 0.f;
#pragma unroll
        for (int q = 0; q < 4; ++q) {
            float4 hv  = *reinterpret_cast<const float4*>(&hs[row][d0 + q * 4]);
            float4 av1 = *reinterpret_cast<const float4*>(a1 + d0 + q * 4);
            float4 av2 = *reinterpret_cast<const float4*>(a2 + d0 + q * 4);
            s1 += hv.x * av1.x + hv.y * av1.y + hv.z * av1.z + hv.w * av1.w;
            s2 += hv.x * av2.x + hv.y * av2.y + hv.z * av2.z + hv.w * av2.w;
        }
#pragma unroll
        for (int off = 1; off < 8; off <<= 1) {
            s1 += __shfl_xor(s1, off, 64);
            s2 += __shfl_xor(s2, off, 64);
        }
        if ((t & 7) == 0) {
            f1[b * NN + r0 + row] = s1;
            f2[b * NN + r0 + row] = s2;
        }
    }

    // panel pack: thread -> n = t>>1, c in {(t&1)*2, (t&1)*2+1}
    {
        int n = t >> 1;
        size_t base = (((size_t)b * 64 + ks) * 128 + n) * 32;
#pragma unroll
        for (int cc = 0; cc < 2; ++cc) {
            int c = (t & 1) * 2 + cc;
            unsigned short u[8];
#pragma unroll
            for (int e = 0; e < 8; ++e) u[e] = bf16_rne(hs[c * 8 + e][n]);
            short8 v;
#pragma unroll
            for (int e = 0; e < 8; ++e) v[e] = (short)u[e];
            *reinterpret_cast<short8*>(panel + base + (size_t)c * 8) = v;
        }
    }
}

// ---------------- Kernel 2: W-gen (regs) + MFMA aggregation ----------------
// Block: 32 rows (2 m-tiles), 4 waves each own a K-quarter (512). No K-loop barriers.
__global__ __launch_bounds__(256, 2) void gat_mfma(const int* __restrict__ adj,
                                                   const float* __restrict__ f1,
                                                   const float* __restrict__ f2,
                                                   const unsigned short* __restrict__ panel,
                                                   float* __restrict__ out) {
    __shared__ float buf[2][32][132];   // 33792 B, col-padded 128->132 (2-way banks)
    __shared__ float sden[4][32];

    int blk  = blockIdx.x;
    int b    = blk & 7;        // XCD-aligned batch
    int tile = blk >> 3;       // 64 tiles per batch
    int i0   = tile * 32;
    int t    = threadIdx.x;
    int w    = t >> 6, l = t & 63;
    int lr   = l & 15, lc = l >> 4;    // fragment row/col lane, k-chunk

    const int* adjb = adj + (size_t)b * NN * NN;
    const unsigned short* pb = panel + (size_t)b * (64 * 128 * 32);
    const float* f2b = f2 + b * NN;
    float f1r0 = f1[b * NN + i0 + lr];
    float f1r1 = f1[b * NN + i0 + 16 + lr];

    f32x4 acc[2][8];
#pragma unroll
    for (int mt = 0; mt < 2; ++mt)
#pragma unroll
        for (int nt = 0; nt < 8; ++nt) acc[mt][nt] = (f32x4){0.f, 0.f, 0.f, 0.f};
    float sacc0 = 0.f, sacc1 = 0.f;

    int kbase = w * 512;
    for (int ks = 0; ks < 16; ++ks) {
        int k0 = kbase + ks * 32;
        int jb = k0 + lc * 8;
        // f2 for my 8 columns
        float4 f2a = *reinterpret_cast<const float4*>(f2b + jb);
        float4 f2c = *reinterpret_cast<const float4*>(f2b + jb + 4);
        // adjacency for my two rows x 8 cols
        const int* ar0 = adjb + (size_t)(i0 + lr) * NN + jb;
        const int* ar1 = ar0 + (size_t)16 * NN;
        int4 a00 = *reinterpret_cast<const int4*>(ar0);
        int4 a01 = *reinterpret_cast<const int4*>(ar0 + 4);
        int4 a10 = *reinterpret_cast<const int4*>(ar1);
        int4 a11 = *reinterpret_cast<const int4*>(ar1 + 4);
        // B fragments: contiguous 1KB per wave per n-tile
        const unsigned short* pk = pb + (size_t)(k0 >> 5) * 4096 + lr * 32 + lc * 8;
        short8 bf[8];
#pragma unroll
        for (int nt = 0; nt < 8; ++nt)
            bf[nt] = *reinterpret_cast<const short8*>(pk + nt * 512);

        float f2v[8] = {f2a.x, f2a.y, f2a.z, f2a.w, f2c.x, f2c.y, f2c.z, f2c.w};
        int aj0[8] = {a00.x, a00.y, a00.z, a00.w, a01.x, a01.y, a01.z, a01.w};
        int aj1[8] = {a10.x, a10.y, a10.z, a10.w, a11.x, a11.y, a11.z, a11.w};

        short8 af0, af1;
#pragma unroll
        for (int e = 0; e < 8; ++e) {
            float x0 = f1r0 + f2v[e];
            float e0 = fmaxf(x0, ALPHA * x0);
            float w0 = (aj0[e] > 0) ? __expf(e0) : 0.f;
            unsigned short u0 = bf16_rne(w0);
            sacc0 += bf16_back(u0);            // denominator from ROUNDED weights
            af0[e] = (short)u0;

            float x1 = f1r1 + f2v[e];
            float e1 = fmaxf(x1, ALPHA * x1);
            float w1 = (aj1[e] > 0) ? __expf(e1) : 0.f;
            unsigned short u1 = bf16_rne(w1);
            sacc1 += bf16_back(u1);
            af1[e] = (short)u1;
        }
#pragma unroll
        for (int nt = 0; nt < 8; ++nt) {
            acc[0][nt] = __builtin_amdgcn_mfma_f32_16x16x32_bf16(af0, bf[nt], acc[0][nt], 0, 0, 0);
            acc[1][nt] = __builtin_amdgcn_mfma_f32_16x16x32_bf16(af1, bf[nt], acc[1][nt], 0, 0, 0);
        }
    }

    // per-wave partial row denominators (reduce 4 k-chunk lane groups)
    sacc0 += __shfl_xor(sacc0, 16, 64); sacc0 += __shfl_xor(sacc0, 32, 64);
    sacc1 += __shfl_xor(sacc1, 16, 64); sacc1 += __shfl_xor(sacc1, 32, 64);
    if (l < 16) { sden[w][l] = sacc0; sden[w][16 + l] = sacc1; }

    // cross-wave K reduction: pair (0,1)->buf0, (2,3)->buf1
    float* mybuf = &buf[w >> 1][0][0];
    if ((w & 1) == 0) {
#pragma unroll
        for (int mt = 0; mt < 2; ++mt)
#pragma unroll
            for (int nt = 0; nt < 8; ++nt) {
                float* p = mybuf + (mt * 16 + lc * 4) * 132 + nt * 16 + lr;
#pragma unroll
                for (int r = 0; r < 4; ++r) p[r * 132] = acc[mt][nt][r];
            }
    }
    __syncthreads();
    if (w & 1) {
#pragma unroll
        for (int mt = 0; mt < 2; ++mt)
#pragma unroll
            for (int nt = 0; nt < 8; ++nt) {
                float* p = mybuf + (mt * 16 + lc * 4) * 132 + nt * 16 + lr;
#pragma unroll
                for (int r = 0; r < 4; ++r) p[r * 132] += acc[mt][nt][r];
            }
    }
    __syncthreads();

    // epilogue: 8 threads per row; out = elu((buf0+buf1)/den)
    {
        int row = t >> 3, col0 = (t & 7) * 16;
        float den = sden[0][row] + sden[1][row] + sden[2][row] + sden[3][row];
        float inv = 1.0f / den;
        float* ob = out + ((size_t)b * NN + i0 + row) * DD;
#pragma unroll
        for (int q = 0; q < 4; ++q) {
            int col = col0 + q * 4;
            const float* p0 = &buf[0][row][col];
            const float* p1 = &buf[1][row][col];
            float4 v0 = *reinterpret_cast<const float4*>(p0);
            float4 v1 = *reinterpret_cast<const float4*>(p1);
            float r0 = (v0.x + v1.x) * inv;
            float r1 = (v0.y + v1.y) * inv;
            float r2 = (v0.z + v1.z) * inv;
            float r3 = (v0.w + v1.w) * inv;
            r0 = (r0 > 0.f) ? r0 : expm1f(r0);
            r1 = (r1 > 0.f) ? r1 : expm1f(r1);
            r2 = (r2 > 0.f) ? r2 : expm1f(r2);
            r3 = (r3 > 0.f) ? r3 : expm1f(r3);
            *reinterpret_cast<float4*>(ob + col) = make_float4(r0, r1, r2, r3);
        }
    }
}

extern "C" void kernel_launch(void* const* d_in, const int* in_sizes, int n_in,
                              void* d_out, int out_size, void* d_ws, size_t ws_size,
                              hipStream_t stream) {
    const float* h   = (const float*)d_in[0];
    const int*   adj = (const int*)d_in[1];
    const float* a1  = (const float*)d_in[2];
    const float* a2  = (const float*)d_in[3];
    float* out = (float*)d_out;

    float* f1 = (float*)d_ws;                                   // 16384 floats
    float* f2 = f1 + BB * NN;                                   // 16384 floats
    unsigned short* panel = (unsigned short*)(f2 + BB * NN);    // 2M bf16 = 4MB

    pack_kernel<<<BB * 64, 256, 0, stream>>>(h, a1, a2, f1, f2, panel);
    gat_mfma<<<BB * 64, 256, 0, stream>>>(adj, f1, f2, panel, out);
}